// Round 2
// baseline (1011.434 us; speedup 1.0000x reference)
//
#include <hip/hip_runtime.h>
#include <stdint.h>

typedef __attribute__((ext_vector_type(8))) __bf16 bf16x8;
typedef __attribute__((ext_vector_type(4))) float floatx4;

#define GLOBAL_AS __attribute__((address_space(1)))
#define LDS_AS __attribute__((address_space(3)))

#define CAP 96          // edge bucket capacity per row (Poisson lambda=16 -> overflow P ~1e-14)
#define N1 15001        // graph rows
#define NPAD 15104      // 118 * 128

__device__ __forceinline__ unsigned short f2bf(float x) {
  unsigned int u = __builtin_bit_cast(unsigned int, x);
  u += 0x7FFFu + ((u >> 16) & 1u);   // round-to-nearest-even
  return (unsigned short)(u >> 16);
}
__device__ __forceinline__ unsigned int pk2(float lo, float hi) {
  return (unsigned)f2bf(lo) | ((unsigned)f2bf(hi) << 16);
}

// Stage a 128x32 bf16 tile (row-major, ld) into LDS chunks[kg][m], kg=k>>3,
// each chunk 16B. global_load_lds w=16: dst = wave-uniform base + lane*16.
__device__ __forceinline__ void stage_tile(const unsigned short* g, int ld, int row0, int k0,
                                           bf16x8* lds, int tid) {
  const int lane = tid & 63;
  const int w = tid >> 6;
#pragma unroll
  for (int j = 0; j < 2; ++j) {
    const int c = j * 256 + w * 64;        // wave-uniform chunk base
    const int kg = c >> 7;
    const int mbase = c & 127;
    const unsigned short* src = g + ((size_t)(row0 + mbase + lane) * ld + k0 + kg * 8);
    __builtin_amdgcn_global_load_lds((const GLOBAL_AS void*)src, (LDS_AS void*)(lds + c),
                                     16, 0, 0);
  }
}

// C = A(MxK) * B(NxK)^T, K=1024, 128x128 tile, 256 thr (4 waves 2x2), 4x4 16x16x32 MFMA.
// MODE 0: A is FP32 (manual convert-stage); epilogue bias+max-over-32rows+relu -> bf16 pooled
// MODE 1: A bf16; epilogue bias+relu -> fp32 outF (ld 1024)
// MODE 2: A bf16; plain fp32 store, ld nValid, col guard
template <int MODE>
__launch_bounds__(256, 2)
__global__ void gemm_bt(const void* __restrict__ Aptr,
                        const unsigned short* __restrict__ Bm,
                        const float* __restrict__ bias,
                        float* __restrict__ outF,
                        unsigned short* __restrict__ outU,
                        int nValid) {
  __shared__ bf16x8 As[512];   // [kg][m] chunks, 8 KB
  __shared__ bf16x8 Bs[512];
  const int tid = threadIdx.x;
  const int lane = tid & 63;
  const int w = tid >> 6;
  const int wm = w >> 1, wn = w & 1;
  const int quad = lane >> 4, col = lane & 15;
  const int m0 = blockIdx.y * 128, n0 = blockIdx.x * 128;
  const int K = 1024;

  floatx4 acc[4][4];
#pragma unroll
  for (int a = 0; a < 4; ++a)
#pragma unroll
    for (int b = 0; b < 4; ++b) acc[a][b] = 0;

  for (int k0 = 0; k0 < K; k0 += 32) {
    __syncthreads();                        // protect LDS from overwrite
    if (MODE == 0) {
      // A is fp32: thread (row=tid>>1, kh=tid&1) loads 16 fp32, converts, writes 2 chunks
      const int row = tid >> 1, kh = tid & 1;
      const float* src = (const float*)Aptr + (size_t)(m0 + row) * K + k0 + kh * 16;
      float4 v0 = ((const float4*)src)[0];
      float4 v1 = ((const float4*)src)[1];
      float4 v2 = ((const float4*)src)[2];
      float4 v3 = ((const float4*)src)[3];
      stage_tile(Bm, K, n0, k0, Bs, tid);   // overlap B DMA with A convert
      uint4 c0, c1;
      c0.x = pk2(v0.x, v0.y); c0.y = pk2(v0.z, v0.w);
      c0.z = pk2(v1.x, v1.y); c0.w = pk2(v1.z, v1.w);
      c1.x = pk2(v2.x, v2.y); c1.y = pk2(v2.z, v2.w);
      c1.z = pk2(v3.x, v3.y); c1.w = pk2(v3.z, v3.w);
      ((uint4*)As)[(kh * 2) * 128 + row] = c0;       // chunk (kg=2kh,   m=row)
      ((uint4*)As)[(kh * 2 + 1) * 128 + row] = c1;   // chunk (kg=2kh+1, m=row)
    } else {
      stage_tile((const unsigned short*)Aptr, K, m0, k0, As, tid);
      stage_tile(Bm, K, n0, k0, Bs, tid);
    }
    __syncthreads();                        // drains vmcnt/lgkmcnt before s_barrier
    bf16x8 af[4], bfr[4];
#pragma unroll
    for (int t = 0; t < 4; ++t) af[t] = As[quad * 128 + wm * 64 + t * 16 + col];
#pragma unroll
    for (int t = 0; t < 4; ++t) bfr[t] = Bs[quad * 128 + wn * 64 + t * 16 + col];
#pragma unroll
    for (int mt = 0; mt < 4; ++mt)
#pragma unroll
      for (int nt = 0; nt < 4; ++nt)
        acc[mt][nt] = __builtin_amdgcn_mfma_f32_16x16x32_bf16(af[mt], bfr[nt], acc[mt][nt], 0, 0, 0);
  }

  // D layout: row = quad*4 + reg, col = lane&15
  if (MODE == 0) {
    float bv[4];
#pragma unroll
    for (int nt = 0; nt < 4; ++nt) bv[nt] = bias[n0 + wn * 64 + nt * 16 + col];
#pragma unroll
    for (int g = 0; g < 2; ++g) {          // two 32-row (one-seq) groups per wave
#pragma unroll
      for (int nt = 0; nt < 4; ++nt) {
        float v = -3.4e38f;
#pragma unroll
        for (int mh = 0; mh < 2; ++mh) {
          const int mt = 2 * g + mh;
#pragma unroll
          for (int r = 0; r < 4; ++r) v = fmaxf(v, acc[mt][nt][r]);
        }
        v += bv[nt];                        // max(x)+b == max(x+b)
        v = fmaxf(v, __shfl_xor(v, 16, 64));
        v = fmaxf(v, __shfl_xor(v, 32, 64));
        v = fmaxf(v, 0.0f);                 // relu after max (monotone)
        if (quad == 0) {
          const int b = (m0 >> 5) + wm * 2 + g;
          outU[b * 1024 + n0 + wn * 64 + nt * 16 + col] = f2bf(v);
        }
      }
    }
  } else if (MODE == 1) {
    float bv[4];
#pragma unroll
    for (int nt = 0; nt < 4; ++nt) bv[nt] = bias[n0 + wn * 64 + nt * 16 + col];
#pragma unroll
    for (int mt = 0; mt < 4; ++mt)
#pragma unroll
      for (int r = 0; r < 4; ++r) {
        const int row = m0 + wm * 64 + mt * 16 + quad * 4 + r;
#pragma unroll
        for (int nt = 0; nt < 4; ++nt)
          outF[(size_t)row * 1024 + n0 + wn * 64 + nt * 16 + col] =
              fmaxf(acc[mt][nt][r] + bv[nt], 0.0f);
      }
  } else {
#pragma unroll
    for (int mt = 0; mt < 4; ++mt)
#pragma unroll
      for (int r = 0; r < 4; ++r) {
        const size_t row = m0 + wm * 64 + mt * 16 + quad * 4 + r;
#pragma unroll
        for (int nt = 0; nt < 4; ++nt) {
          const int cg = n0 + wn * 64 + nt * 16 + col;
          if (cg < nValid) outF[row * (size_t)nValid + cg] = acc[mt][nt][r];
        }
      }
  }
}

__global__ void f32_to_bf16(const float* __restrict__ in, unsigned short* __restrict__ out, int n4) {
  const int i = blockIdx.x * 256 + threadIdx.x;   // 4 elements per thread
  if (i >= n4) return;
  const float4 v = ((const float4*)in)[i];
  uint2 p;
  p.x = pk2(v.x, v.y);
  p.y = pk2(v.z, v.w);
  ((uint2*)out)[i] = p;
}

__global__ void bucket_fill(const int* __restrict__ rows, int nnz,
                            int* __restrict__ cnt, int* __restrict__ bucket) {
  const int e = blockIdx.x * 256 + threadIdx.x;
  if (e >= nnz) return;
  const int r = rows[e];
  if ((unsigned)r >= (unsigned)N1) return;
  const int pos = atomicAdd(&cnt[r], 1);
  if (pos < CAP) bucket[r * CAP + pos] = e;
}

// one block (256 thr) per graph row; thread t owns cols 4t..4t+3 (fp32 H0)
__global__ void build_graph(const int* __restrict__ cols,
                            const float* __restrict__ values,
                            const float* __restrict__ H0,
                            const float* __restrict__ gbias,
                            const int* __restrict__ cnt,
                            const int* __restrict__ bucket,
                            unsigned short* __restrict__ graph) {
  __shared__ int s_col[CAP];
  __shared__ float s_val[CAP];
  const int r = blockIdx.x;
  const int t = threadIdx.x;
  int n = (r < N1) ? cnt[r] : 0;
  if (n > CAP) n = CAP;
  if (t < n) {
    const int e = bucket[r * CAP + t];
    s_col[t] = cols[e];
    s_val[t] = values[e];
  }
  __syncthreads();
  float4 a = *(const float4*)(gbias + t * 4);
  for (int i = 0; i < n; ++i) {
    const int c = s_col[i];
    const float f = s_val[i];
    const float4 hv = *(const float4*)(H0 + (size_t)c * 1024 + t * 4);
    a.x += f * hv.x;
    a.y += f * hv.y;
    a.z += f * hv.z;
    a.w += f * hv.w;
  }
  uint2 p;
  p.x = pk2(a.x, a.y);
  p.y = pk2(a.z, a.w);
  *(uint2*)(graph + (size_t)r * 1024 + t * 4) = p;
}

__global__ void normalize_rows(const float* __restrict__ x, unsigned short* __restrict__ phrase) {
  const int b = blockIdx.x;
  const int t = threadIdx.x;
  const float4 v = *(const float4*)(x + (size_t)b * 1024 + t * 4);
  float ss = v.x * v.x + v.y * v.y + v.z * v.z + v.w * v.w;
#pragma unroll
  for (int o = 32; o > 0; o >>= 1) ss += __shfl_down(ss, o, 64);
  __shared__ float sred[4];
  if ((t & 63) == 0) sred[t >> 6] = ss;
  __syncthreads();
  const float tot = sred[0] + sred[1] + sred[2] + sred[3];
  const float inv = 1.0f / fmaxf(sqrtf(tot), 1e-12f);
  uint2 p;
  p.x = pk2(v.x * inv, v.y * inv);
  p.y = pk2(v.z * inv, v.w * inv);
  *(uint2*)(phrase + (size_t)b * 1024 + t * 4) = p;
}

extern "C" void kernel_launch(void* const* d_in, const int* in_sizes, int n_in,
                              void* d_out, int out_size, void* d_ws, size_t ws_size,
                              hipStream_t stream) {
  const float* data   = (const float*)d_in[0];   // (2048,32,1024) fp32
  // d_in[1] = seq_len: unused by the reference
  const float* conv_w = (const float*)d_in[2];   // (1024,1024) fp32
  const float* conv_b = (const float*)d_in[3];   // (1024,) fp32
  const float* lin_w  = (const float*)d_in[4];   // (1024,1024) fp32
  const float* lin_b  = (const float*)d_in[5];   // (1024,) fp32
  const float* gbias  = (const float*)d_in[6];   // (1024,) fp32
  const float* H0     = (const float*)d_in[7];   // (15001,1024) fp32
  const int* indices  = (const int*)d_in[8];     // (2, NNZ) int32
  const float* values = (const float*)d_in[9];   // (NNZ,) fp32
  float* out = (float*)d_out;                    // (2048,15001) fp32

  const int NNZ = in_sizes[9];

  char* ws = (char*)d_ws;
  unsigned short* conv_wb = (unsigned short*)ws; ws += (size_t)1024 * 1024 * 2;  // 2 MB
  unsigned short* lin_wb  = (unsigned short*)ws; ws += (size_t)1024 * 1024 * 2;  // 2 MB
  unsigned short* pooled  = (unsigned short*)ws; ws += (size_t)2048 * 1024 * 2;  // 4 MB
  float* xbuf             = (float*)ws;          ws += (size_t)2048 * 1024 * 4;  // 8 MB
  unsigned short* phrase  = (unsigned short*)ws; ws += (size_t)2048 * 1024 * 2;  // 4 MB
  unsigned short* graph   = (unsigned short*)ws; ws += (size_t)NPAD * 1024 * 2;  // ~31 MB
  int* cnt                = (int*)ws;            ws += (size_t)NPAD * 4;
  int* bucket             = (int*)ws;            ws += (size_t)NPAD * CAP * 4;   // ~5.8 MB

  // --- weight conversion fp32 -> bf16 ---
  f32_to_bf16<<<1024, 256, 0, stream>>>(conv_w, conv_wb, 1024 * 1024 / 4);
  f32_to_bf16<<<1024, 256, 0, stream>>>(lin_w, lin_wb, 1024 * 1024 / 4);

  // --- sparse graph build ---
  hipMemsetAsync(cnt, 0, (size_t)NPAD * 4, stream);
  bucket_fill<<<(NNZ + 255) / 256, 256, 0, stream>>>(indices, NNZ, cnt, bucket);
  build_graph<<<NPAD, 256, 0, stream>>>(indices + NNZ, values, H0, gbias, cnt, bucket, graph);

  // --- CNN phrase encoder ---
  gemm_bt<0><<<dim3(8, 512), 256, 0, stream>>>(data, conv_wb, conv_b, nullptr, pooled, 1024);
  gemm_bt<1><<<dim3(8, 16), 256, 0, stream>>>(pooled, lin_wb, lin_b, xbuf, nullptr, 1024);
  normalize_rows<<<2048, 256, 0, stream>>>(xbuf, phrase);

  // --- bilinear score ---
  gemm_bt<2><<<dim3(118, 16), 256, 0, stream>>>(phrase, graph, nullptr, out, nullptr, N1);
}